// Round 14
// baseline (795.934 us; speedup 1.0000x reference)
//
#include <hip/hip_runtime.h>
#include <hip/hip_bf16.h>

#define SEQ    2048
#define DMODEL 2048
#define NHEAD  16
#define DHEAD  128
#define TOK    4096   // B*S
#define TD     6144   // 3*D
#define FFDIM  8192

typedef __attribute__((ext_vector_type(4)))  float f32x4;
typedef __attribute__((ext_vector_type(16))) float f32x16;
typedef __attribute__((ext_vector_type(8)))  short short8v;

__device__ __forceinline__ void async_ld16(const void* src, void* lds) {
  __builtin_amdgcn_global_load_lds((const __attribute__((address_space(1))) void*)src,
                                   (__attribute__((address_space(3))) void*)lds, 16, 0, 0);
}

__device__ __forceinline__ unsigned pk2(float a, float b) {
  union { __hip_bfloat16 h[2]; unsigned u; } p;
  p.h[0] = __float2bfloat16(a);
  p.h[1] = __float2bfloat16(b);
  return p.u;
}

// ---------------------------------------------------------------- fp32 -> bf16
__global__ __launch_bounds__(256) void f2bf_kernel(const float* __restrict__ in,
                                                   __hip_bfloat16* __restrict__ out, long n) {
  long i0 = ((long)blockIdx.x * 256 + threadIdx.x) * 8;
  long stride = (long)gridDim.x * 256 * 8;
  for (long i = i0; i < n; i += stride) {
    float4 a = *(const float4*)(in + i);
    float4 b = *(const float4*)(in + i + 4);
    union { __hip_bfloat16 h[8]; int4 v; } p;
    p.h[0] = __float2bfloat16(a.x); p.h[1] = __float2bfloat16(a.y);
    p.h[2] = __float2bfloat16(a.z); p.h[3] = __float2bfloat16(a.w);
    p.h[4] = __float2bfloat16(b.x); p.h[5] = __float2bfloat16(b.y);
    p.h[6] = __float2bfloat16(b.z); p.h[7] = __float2bfloat16(b.w);
    *(int4*)(out + i) = p.v;
  }
}

// ---------------------------------------------------------------- LayerNorm -> bf16
__global__ __launch_bounds__(256) void ln_kernel(const float* __restrict__ x,
                                                 const float* __restrict__ w,
                                                 const float* __restrict__ b,
                                                 __hip_bfloat16* __restrict__ out) {
  __shared__ float red[8];
  const int row = blockIdx.x;
  const int tid = threadIdx.x;
  const float* xr = x + (long)row * DMODEL;
  float4 v0 = ((const float4*)xr)[tid * 2];
  float4 v1 = ((const float4*)xr)[tid * 2 + 1];
  float s  = v0.x + v0.y + v0.z + v0.w + v1.x + v1.y + v1.z + v1.w;
  float ss = v0.x*v0.x + v0.y*v0.y + v0.z*v0.z + v0.w*v0.w
           + v1.x*v1.x + v1.y*v1.y + v1.z*v1.z + v1.w*v1.w;
  #pragma unroll
  for (int m = 1; m < 64; m <<= 1) { s += __shfl_xor(s, m, 64); ss += __shfl_xor(ss, m, 64); }
  if ((tid & 63) == 0) { red[tid >> 6] = s; red[4 + (tid >> 6)] = ss; }
  __syncthreads();
  s  = red[0] + red[1] + red[2] + red[3];
  ss = red[4] + red[5] + red[6] + red[7];
  const float mu = s * (1.0f / DMODEL);
  const float rs = rsqrtf(ss * (1.0f / DMODEL) - mu * mu + 1e-5f);
  float4 w0 = ((const float4*)w)[tid * 2], w1 = ((const float4*)w)[tid * 2 + 1];
  float4 b0 = ((const float4*)b)[tid * 2], b1 = ((const float4*)b)[tid * 2 + 1];
  union { __hip_bfloat16 h[8]; int4 v; } p;
  p.h[0] = __float2bfloat16((v0.x - mu) * rs * w0.x + b0.x);
  p.h[1] = __float2bfloat16((v0.y - mu) * rs * w0.y + b0.y);
  p.h[2] = __float2bfloat16((v0.z - mu) * rs * w0.z + b0.z);
  p.h[3] = __float2bfloat16((v0.w - mu) * rs * w0.w + b0.w);
  p.h[4] = __float2bfloat16((v1.x - mu) * rs * w1.x + b1.x);
  p.h[5] = __float2bfloat16((v1.y - mu) * rs * w1.y + b1.y);
  p.h[6] = __float2bfloat16((v1.z - mu) * rs * w1.z + b1.z);
  p.h[7] = __float2bfloat16((v1.w - mu) * rs * w1.w + b1.w);
  ((int4*)(out + (long)row * DMODEL))[tid] = p.v;
}

// ---------------------------------------------------------------- GEMM  C = A * B^T (+epilogue)
// R1-verified m97-class kernel: 128x128 tile, 4 waves, BK=64, 32KB LDS ->
// 4 blocks/CU co-resident (occupancy-driven overlap, m114). Only change vs R1:
// T1 bijective XCD block remap (grids all %8==0).
// MODE 0: bf16 out = acc + bias ; 1: f32 out = acc + bias + resid ; 2: bf16 gelu(acc+bias)
template <int MODE>
__global__ __launch_bounds__(256) void gemm_bt(const __hip_bfloat16* __restrict__ A,
                                               const __hip_bfloat16* __restrict__ B,
                                               const float* __restrict__ bias,
                                               const float* __restrict__ resid,
                                               void* __restrict__ outp,
                                               int N, long K) {
  __shared__ __align__(16) char lds[32768];   // A tile [128][64] @0, B tile @16384, swizzled rows
  const int tid = threadIdx.x;
  const int lane = tid & 63;
  const int wid = tid >> 6;
  const int wr = wid >> 1, wc = wid & 1;
  // T1: bijective XCD remap
  const int gx = gridDim.x;
  const int nwg = gx * (int)gridDim.y;
  const int lin = (int)blockIdx.y * gx + (int)blockIdx.x;
  const int cpx = nwg >> 3;
  const int swz = (lin & 7) * cpx + (lin >> 3);
  const long m0 = (long)(swz / gx) * 128;
  const long n0 = (long)(swz % gx) * 128;

  const int lrow = lane >> 3;                     // 0..7
  const long ksrc = (long)(((lane & 7) ^ lrow) * 8);  // pre-swizzled k source (elements)

  f32x4 acc[4][4] = {};

  for (long kt = 0; kt < K; kt += 64) {
    __syncthreads();
    #pragma unroll
    for (int c = 0; c < 8; ++c) {
      int region = wid * 8 + c;          // 0..31 ; 0..15 -> A, 16..31 -> B
      int isB = region >> 4;
      int rr = region & 15;
      int row = rr * 8 + lrow;           // 0..127 tile row
      const __hip_bfloat16* srcbase = isB ? B : A;
      long grow = (isB ? n0 : m0) + row;
      const __hip_bfloat16* src = srcbase + grow * K + kt + ksrc;
      async_ld16(src, lds + isB * 16384 + rr * 1024);
    }
    __syncthreads();
    #pragma unroll
    for (int kk = 0; kk < 2; ++kk) {
      short8v af[4], bfr[4];
      #pragma unroll
      for (int m = 0; m < 4; ++m) {
        int row = wr * 64 + m * 16 + (lane & 15);
        int kb = kk * 64 + (lane >> 4) * 16;
        af[m] = *(const short8v*)(lds + row * 128 + (kb ^ ((row & 7) << 4)));
      }
      #pragma unroll
      for (int n = 0; n < 4; ++n) {
        int row = wc * 64 + n * 16 + (lane & 15);
        int kb = kk * 64 + (lane >> 4) * 16;
        bfr[n] = *(const short8v*)(lds + 16384 + row * 128 + (kb ^ ((row & 7) << 4)));
      }
      #pragma unroll
      for (int m = 0; m < 4; ++m)
        #pragma unroll
        for (int n = 0; n < 4; ++n)
          acc[m][n] = __builtin_amdgcn_mfma_f32_16x16x32_bf16(af[m], bfr[n], acc[m][n], 0, 0, 0);
    }
  }

  const int colq = lane & 15;
  const int rowq = (lane >> 4) * 4;
  #pragma unroll
  for (int n = 0; n < 4; ++n) {
    long col = n0 + wc * 64 + n * 16 + colq;
    float bi = bias[col];
    #pragma unroll
    for (int m = 0; m < 4; ++m) {
      long row0 = m0 + wr * 64 + m * 16 + rowq;
      #pragma unroll
      for (int j = 0; j < 4; ++j) {
        long idx = (row0 + j) * (long)N + col;
        float v = acc[m][n][j] + bi;
        if (MODE == 0) {
          ((__hip_bfloat16*)outp)[idx] = __float2bfloat16(v);
        } else if (MODE == 1) {
          ((float*)outp)[idx] = v + resid[idx];
        } else {
          float g = 0.5f * v * (1.0f + erff(v * 0.70710678118654752f));
          ((__hip_bfloat16*)outp)[idx] = __float2bfloat16(g);
        }
      }
    }
  }
}

// ---------------------------------------------------------------- causal flash attention (R10-passing)
// qb-paired load balance: grid (8, 32); block bx does q-tiles {15-bx, bx}.
#define QBLK 128
#define KVB  64
#define VSTR 144                      // Vt row stride bytes (72 elems)
#define KBYT 16384                    // K buffer bytes
#define VBYT (DHEAD * VSTR)           // 18432
__global__ __launch_bounds__(256, 2) void attn_kernel(const __hip_bfloat16* __restrict__ qkv,
                                                      __hip_bfloat16* __restrict__ out) {
  __shared__ __align__(16) char smem[2 * KBYT + 2 * VBYT];
  const int tid = threadIdx.x, lane = tid & 63, wid = tid >> 6;
  const int l31 = lane & 31, hi = lane >> 5;
  const int bx = blockIdx.x;
  const int bh = blockIdx.y;
  const int bb = bh >> 4, h = bh & 15;
  const long rowbase = (long)bb * SEQ;
  const int qcol = h * DHEAD, kcol = DMODEL + h * DHEAD, vcol = 2 * DMODEL + h * DHEAD;

  const int kv0s = (tid >> 4) * 4;
  const int dh0s = (tid & 15) * 8;
  auto k_stage = [&](int t) {
    char* kb = smem + (t & 1) * KBYT;
    const long kvr = rowbase + (long)t * KVB;
    #pragma unroll
    for (int i = 0; i < 4; ++i) {
      int c = i * 256 + tid;
      int row = c >> 4, slot = c & 15;
      const void* src = qkv + (kvr + row) * TD + kcol + ((slot ^ (row & 7)) << 3);
      async_ld16(src, kb + i * 4096 + wid * 1024);
    }
  };
  auto v_load = [&](int t, int4* r) {
    const long kvr = rowbase + (long)t * KVB;
    #pragma unroll
    for (int i = 0; i < 4; ++i)
      r[i] = *(const int4*)(qkv + (kvr + kv0s + i) * TD + vcol + dh0s);
  };
  auto v_write = [&](int t, const int4* r) {
    char* vt = smem + 2 * KBYT + (t & 1) * VBYT;
    union { int4 v; unsigned short s[8]; } u0, u1, u2, u3;
    u0.v = r[0]; u1.v = r[1]; u2.v = r[2]; u3.v = r[3];
    #pragma unroll
    for (int dd = 0; dd < 8; ++dd) {
      int d = (dd + ((tid >> 1) & 7)) & 7;
      unsigned lo = (unsigned)u0.s[d] | ((unsigned)u1.s[d] << 16);
      unsigned hi2 = (unsigned)u2.s[d] | ((unsigned)u3.s[d] << 16);
      uint2 wv; wv.x = lo; wv.y = hi2;
      *(uint2*)(vt + (dh0s + d) * VSTR + kv0s * 2) = wv;
    }
  };

  #pragma unroll
  for (int mem = 0; mem < 2; ++mem) {
    const int qb = mem == 0 ? (15 - bx) : bx;   // long member first
    const int q0 = qb * QBLK;
    const int qw0 = q0 + wid * 32;

    short8v qf[8];
    {
      const __hip_bfloat16* qp = qkv + (rowbase + qw0 + l31) * TD + qcol + hi * 8;
      #pragma unroll
      for (int kc = 0; kc < 8; ++kc) qf[kc] = *(const short8v*)(qp + kc * 16);
    }

    f32x16 o[4] = {};
    float m_ = -1e30f, l_ = 0.0f;
    const int nt = (q0 + QBLK) / KVB;

    {
      int4 vr[4];
      v_load(0, vr);
      k_stage(0);
      v_write(0, vr);
    }
    __syncthreads();

    for (int t = 0; t < nt; ++t) {
      int4 vr[4];
      const bool more = (t + 1 < nt);
      if (more) { v_load(t + 1, vr); k_stage(t + 1); }

      const int kv0 = t * KVB;
      if (kv0 <= qw0 + 31) {
        const char* Kb = smem + (t & 1) * KBYT;
        f32x16 s0 = {}, s1 = {};
        #pragma unroll
        for (int kc = 0; kc < 8; ++kc) {
          const int colb = kc * 32 + hi * 16;
          const int r0 = l31, r1 = 32 + l31;
          short8v k0 = *(const short8v*)(Kb + r0 * 256 + (colb ^ ((r0 & 7) << 4)));
          short8v k1 = *(const short8v*)(Kb + r1 * 256 + (colb ^ ((r0 & 7) << 4)));
          s0 = __builtin_amdgcn_mfma_f32_32x32x16_bf16(k0, qf[kc], s0, 0, 0, 0);
          s1 = __builtin_amdgcn_mfma_f32_32x32x16_bf16(k1, qf[kc], s1, 0, 0, 0);
        }
        const float scale = 0.08838834764831845f;
        float sv[32];
        #pragma unroll
        for (int r = 0; r < 16; ++r) { sv[r] = s0[r] * scale; sv[16 + r] = s1[r] * scale; }
        const int qg = qw0 + l31;
        if (kv0 + KVB - 1 > qw0) {
          #pragma unroll
          for (int r = 0; r < 16; ++r) {
            int kvr_ = kv0 + (r & 3) + 8 * (r >> 2) + 4 * hi;
            if (kvr_ > qg)      sv[r]      = -1e30f;
            if (kvr_ + 32 > qg) sv[16 + r] = -1e30f;
          }
        }
        float pmax = sv[0];
        #pragma unroll
        for (int r = 1; r < 32; ++r) pmax = fmaxf(pmax, sv[r]);
        pmax = fmaxf(pmax, __shfl_xor(pmax, 32, 64));
        float mn = fmaxf(m_, pmax);
        float alpha = __expf(m_ - mn);
        m_ = mn;
        l_ *= alpha;
        #pragma unroll
        for (int d = 0; d < 4; ++d)
          #pragma unroll
          for (int r = 0; r < 16; ++r) o[d][r] *= alpha;
        float rsum = 0.0f;
        #pragma unroll
        for (int r = 0; r < 32; ++r) { sv[r] = __expf(sv[r] - m_); rsum += sv[r]; }
        l_ += rsum + __shfl_xor(rsum, 32, 64);
        int pa_[4][4];
        #pragma unroll
        for (int kc = 0; kc < 4; ++kc) {
          int ba = 16 * (kc >> 1) + 8 * (kc & 1);
          unsigned wA0 = pk2(sv[ba + 0], sv[ba + 1]);
          unsigned wA1 = pk2(sv[ba + 2], sv[ba + 3]);
          unsigned wB0 = pk2(sv[ba + 4], sv[ba + 5]);
          unsigned wB1 = pk2(sv[ba + 6], sv[ba + 7]);
          unsigned z0 = (unsigned)__shfl_xor((int)(hi ? wA0 : wB0), 32, 64);
          unsigned z1 = (unsigned)__shfl_xor((int)(hi ? wA1 : wB1), 32, 64);
          pa_[kc][0] = hi ? (int)z0 : (int)wA0;
          pa_[kc][1] = hi ? (int)z1 : (int)wA1;
          pa_[kc][2] = hi ? (int)wB0 : (int)z0;
          pa_[kc][3] = hi ? (int)wB1 : (int)z1;
        }
        const char* Vt = smem + 2 * KBYT + (t & 1) * VBYT;
        #pragma unroll
        for (int dht = 0; dht < 4; ++dht) {
          const int dh = dht * 32 + l31;
          short8v vf[4];
          #pragma unroll
          for (int kc = 0; kc < 4; ++kc)
            vf[kc] = *(const short8v*)(Vt + dh * VSTR + kc * 32 + hi * 16);
          #pragma unroll
          for (int kc = 0; kc < 4; ++kc) {
            union { int i[4]; short8v v; } bv;
            bv.i[0] = pa_[kc][0]; bv.i[1] = pa_[kc][1];
            bv.i[2] = pa_[kc][2]; bv.i[3] = pa_[kc][3];
            o[dht] = __builtin_amdgcn_mfma_f32_32x32x16_bf16(vf[kc], bv.v, o[dht], 0, 0, 0);
          }
        }
      }
      if (more) v_write(t + 1, vr);
      __syncthreads();
    }

    const float linv = 1.0f / l_;
    const long orow = (rowbase + qw0 + l31) * DMODEL + h * DHEAD;
    #pragma unroll
    for (int dht = 0; dht < 4; ++dht)
      #pragma unroll
      for (int rg = 0; rg < 4; ++rg) {
        union { __hip_bfloat16 hh[4]; uint2 u; } pk;
        #pragma unroll
        for (int i = 0; i < 4; ++i) pk.hh[i] = __float2bfloat16(o[dht][rg * 4 + i] * linv);
        *(uint2*)(out + orow + dht * 32 + 8 * rg + 4 * hi) = pk.u;
      }
  }
}

// ---------------------------------------------------------------- launch
extern "C" void kernel_launch(void* const* d_in, const int* in_sizes, int n_in,
                              void* d_out, int out_size, void* d_ws, size_t ws_size,
                              hipStream_t stream) {
  const float* hidden  = (const float*)d_in[0];
  const float* ln1w    = (const float*)d_in[1];
  const float* ln1b    = (const float*)d_in[2];
  const float* qkvw    = (const float*)d_in[3];
  const float* qkvb    = (const float*)d_in[4];
  const float* densew  = (const float*)d_in[5];
  const float* denseb  = (const float*)d_in[6];
  const float* ln2w    = (const float*)d_in[7];
  const float* ln2b    = (const float*)d_in[8];
  const float* fc1w    = (const float*)d_in[9];
  const float* fc1b    = (const float*)d_in[10];
  const float* fc2w    = (const float*)d_in[11];
  const float* fc2b    = (const float*)d_in[12];

  char* ws = (char*)d_ws;
  size_t off = 0;
  auto alloc = [&](size_t bytes) { char* p = ws + off; off += (bytes + 255) & ~(size_t)255; return p; };
  __hip_bfloat16* xbf    = (__hip_bfloat16*)alloc((size_t)TOK * DMODEL * 2);
  __hip_bfloat16* wqkv   = (__hip_bfloat16*)alloc((size_t)TD * DMODEL * 2);
  __hip_bfloat16* wdense = (__hip_bfloat16*)alloc((size_t)DMODEL * DMODEL * 2);
  __hip_bfloat16* wfc1   = (__hip_bfloat16*)alloc((size_t)FFDIM * DMODEL * 2);
  __hip_bfloat16* wfc2   = (__hip_bfloat16*)alloc((size_t)DMODEL * FFDIM * 2);
  __hip_bfloat16* big    = (__hip_bfloat16*)alloc((size_t)TOK * FFDIM * 2);
  float*          x2     = (float*)alloc((size_t)TOK * DMODEL * 4);
  __hip_bfloat16* qkvbuf  = big;
  __hip_bfloat16* attnout = big + (size_t)TOK * TD;
  __hip_bfloat16* gelubuf = big;

  f2bf_kernel<<<1024, 256, 0, stream>>>(qkvw,   wqkv,   (long)TD * DMODEL);
  f2bf_kernel<<<1024, 256, 0, stream>>>(densew, wdense, (long)DMODEL * DMODEL);
  f2bf_kernel<<<1024, 256, 0, stream>>>(fc1w,   wfc1,   (long)FFDIM * DMODEL);
  f2bf_kernel<<<1024, 256, 0, stream>>>(fc2w,   wfc2,   (long)DMODEL * FFDIM);

  ln_kernel<<<TOK, 256, 0, stream>>>(hidden, ln1w, ln1b, xbf);
  // QKV: 48x32 = 1536 blocks
  gemm_bt<0><<<dim3(TD / 128, TOK / 128), 256, 0, stream>>>(xbf, wqkv, qkvb, nullptr, qkvbuf, TD, DMODEL);
  attn_kernel<<<dim3(8, 2 * NHEAD), 256, 0, stream>>>(qkvbuf, attnout);
  // dense + residual: 16x32 = 512 blocks
  gemm_bt<1><<<dim3(DMODEL / 128, TOK / 128), 256, 0, stream>>>(attnout, wdense, denseb, hidden, x2, DMODEL, DMODEL);
  ln_kernel<<<TOK, 256, 0, stream>>>(x2, ln2w, ln2b, xbf);
  // FC1 + GELU: 64x32 = 2048 blocks
  gemm_bt<2><<<dim3(FFDIM / 128, TOK / 128), 256, 0, stream>>>(xbf, wfc1, fc1b, nullptr, gelubuf, FFDIM, DMODEL);
  // FC2 + residual -> d_out: 16x32 = 512 blocks
  gemm_bt<1><<<dim3(DMODEL / 128, TOK / 128), 256, 0, stream>>>(gelubuf, wfc2, fc2b, x2, (float*)d_out, DMODEL, FFDIM);
}

// Round 16
// 672.284 us; speedup vs baseline: 1.1839x; 1.1839x over previous
//
#include <hip/hip_runtime.h>
#include <hip/hip_bf16.h>

#define SEQ    2048
#define DMODEL 2048
#define NHEAD  16
#define DHEAD  128
#define TOK    4096   // B*S
#define TD     6144   // 3*D
#define FFDIM  8192

typedef __attribute__((ext_vector_type(4)))  float f32x4;
typedef __attribute__((ext_vector_type(16))) float f32x16;
typedef __attribute__((ext_vector_type(8)))  short short8v;

__device__ __forceinline__ void async_ld16(const void* src, void* lds) {
  __builtin_amdgcn_global_load_lds((const __attribute__((address_space(1))) void*)src,
                                   (__attribute__((address_space(3))) void*)lds, 16, 0, 0);
}

// pack two f32 -> one u32 of 2 bf16, explicit element order (low short = a)
__device__ __forceinline__ unsigned pk2(float a, float b) {
  union { __hip_bfloat16 h[2]; unsigned u; } p;
  p.h[0] = __float2bfloat16(a);
  p.h[1] = __float2bfloat16(b);
  return p.u;
}

// ---------------------------------------------------------------- fp32 -> bf16
__global__ __launch_bounds__(256) void f2bf_kernel(const float* __restrict__ in,
                                                   __hip_bfloat16* __restrict__ out, long n) {
  long i0 = ((long)blockIdx.x * 256 + threadIdx.x) * 8;
  long stride = (long)gridDim.x * 256 * 8;
  for (long i = i0; i < n; i += stride) {
    float4 a = *(const float4*)(in + i);
    float4 b = *(const float4*)(in + i + 4);
    union { __hip_bfloat16 h[8]; int4 v; } p;
    p.h[0] = __float2bfloat16(a.x); p.h[1] = __float2bfloat16(a.y);
    p.h[2] = __float2bfloat16(a.z); p.h[3] = __float2bfloat16(a.w);
    p.h[4] = __float2bfloat16(b.x); p.h[5] = __float2bfloat16(b.y);
    p.h[6] = __float2bfloat16(b.z); p.h[7] = __float2bfloat16(b.w);
    *(int4*)(out + i) = p.v;
  }
}

// ---------------------------------------------------------------- LayerNorm -> bf16
__global__ __launch_bounds__(256) void ln_kernel(const float* __restrict__ x,
                                                 const float* __restrict__ w,
                                                 const float* __restrict__ b,
                                                 __hip_bfloat16* __restrict__ out) {
  __shared__ float red[8];
  const int row = blockIdx.x;
  const int tid = threadIdx.x;
  const float* xr = x + (long)row * DMODEL;
  float4 v0 = ((const float4*)xr)[tid * 2];
  float4 v1 = ((const float4*)xr)[tid * 2 + 1];
  float s  = v0.x + v0.y + v0.z + v0.w + v1.x + v1.y + v1.z + v1.w;
  float ss = v0.x*v0.x + v0.y*v0.y + v0.z*v0.z + v0.w*v0.w
           + v1.x*v1.x + v1.y*v1.y + v1.z*v1.z + v1.w*v1.w;
  #pragma unroll
  for (int m = 1; m < 64; m <<= 1) { s += __shfl_xor(s, m, 64); ss += __shfl_xor(ss, m, 64); }
  if ((tid & 63) == 0) { red[tid >> 6] = s; red[4 + (tid >> 6)] = ss; }
  __syncthreads();
  s  = red[0] + red[1] + red[2] + red[3];
  ss = red[4] + red[5] + red[6] + red[7];
  const float mu = s * (1.0f / DMODEL);
  const float rs = rsqrtf(ss * (1.0f / DMODEL) - mu * mu + 1e-5f);
  float4 w0 = ((const float4*)w)[tid * 2], w1 = ((const float4*)w)[tid * 2 + 1];
  float4 b0 = ((const float4*)b)[tid * 2], b1 = ((const float4*)b)[tid * 2 + 1];
  union { __hip_bfloat16 h[8]; int4 v; } p;
  p.h[0] = __float2bfloat16((v0.x - mu) * rs * w0.x + b0.x);
  p.h[1] = __float2bfloat16((v0.y - mu) * rs * w0.y + b0.y);
  p.h[2] = __float2bfloat16((v0.z - mu) * rs * w0.z + b0.z);
  p.h[3] = __float2bfloat16((v0.w - mu) * rs * w0.w + b0.w);
  p.h[4] = __float2bfloat16((v1.x - mu) * rs * w1.x + b1.x);
  p.h[5] = __float2bfloat16((v1.y - mu) * rs * w1.y + b1.y);
  p.h[6] = __float2bfloat16((v1.z - mu) * rs * w1.z + b1.z);
  p.h[7] = __float2bfloat16((v1.w - mu) * rs * w1.w + b1.w);
  ((int4*)(out + (long)row * DMODEL))[tid] = p.v;
}

// ---------------------------------------------------------------- 256x128 read-ahead GEMM (all GEMMs)
// R11-VERBATIM schedule (verified passing, 656.9us). ONLY change: no XCD remap
// (natural blockIdx order). Derived gates: P1 vm4, P2 vm2, P3 vm4, P4 vm2.
#define VMBAR(N) asm volatile("s_waitcnt vmcnt(" #N ")\ns_barrier" ::: "memory")
#define LGK(N)   do { asm volatile("s_waitcnt lgkmcnt(" #N ")" ::: "memory"); \
                      __builtin_amdgcn_sched_barrier(0); } while (0)

#define RA_READ_A(DST, BB, MH) \
  _Pragma("unroll") \
  for (int m = 0; m < 4; ++m) { \
    int row = wr * 128 + (MH) * 64 + m * 16 + l15; \
    _Pragma("unroll") \
    for (int kk = 0; kk < 2; ++kk) \
      DST[m][kk] = *(const short8v*)((BB) + row * 128 + ((((kk << 2) | c16) ^ (row & 7)) << 4)); \
  }
#define RA_READ_B(DST, BB) \
  _Pragma("unroll") \
  for (int n = 0; n < 2; ++n) { \
    int row = wc * 32 + n * 16 + l15; \
    _Pragma("unroll") \
    for (int kk = 0; kk < 2; ++kk) \
      DST[n][kk] = *(const short8v*)((BB) + 32768 + row * 128 + ((((kk << 2) | c16) ^ (row & 7)) << 4)); \
  }
#define RA_MFMA(AF, BF, MH) \
  __builtin_amdgcn_s_setprio(1); \
  _Pragma("unroll") \
  for (int m = 0; m < 4; ++m) \
    _Pragma("unroll") \
    for (int n = 0; n < 2; ++n) \
      _Pragma("unroll") \
      for (int kk = 0; kk < 2; ++kk) \
        acc[(MH) * 4 + m][n] = __builtin_amdgcn_mfma_f32_16x16x32_bf16( \
            AF[m][kk], BF[n][kk], acc[(MH) * 4 + m][n], 0, 0, 0); \
  __builtin_amdgcn_s_setprio(0);

template <int MODE>
__global__ __launch_bounds__(512, 2) void gemm128ra(const __hip_bfloat16* __restrict__ A,
                                                    const __hip_bfloat16* __restrict__ B,
                                                    const float* __restrict__ bias,
                                                    const float* __restrict__ resid,
                                                    void* __restrict__ outp,
                                                    int N, long K) {
  __shared__ __align__(16) char lds[98304];   // 2 x (A 32KB | B 16KB)
  const int tid = threadIdx.x;
  const int lane = tid & 63, w = tid >> 6;
  const int wr = w >> 2, wc = w & 3;
  const int l15 = lane & 15, c16 = lane >> 4;
  const long m0 = (long)blockIdx.y * 256;
  const long n0 = (long)blockIdx.x * 128;
  const int NT = (int)(K >> 6);
  const int NI = NT >> 1;

  auto stA2 = [&](int t, int par) {           // par 0: quarters {0,2}; 1: {1,3}
    char* base = lds + (t & 1) * 49152;
    #pragma unroll
    for (int j = 0; j < 2; ++j) {
      int q = 2 * j + par;
      int row = q * 64 + (tid >> 3);
      long col = (long)t * 64 + (((tid & 7) ^ (row & 7)) << 3);
      async_ld16(A + (m0 + row) * K + col, base + q * 8192 + w * 1024);
    }
  };
  auto stB1 = [&](int t) {                    // full 128-row B tile (16KB)
    char* base = lds + (t & 1) * 49152 + 32768;
    #pragma unroll
    for (int j = 0; j < 2; ++j) {
      int row = j * 64 + (tid >> 3);
      long col = (long)t * 64 + (((tid & 7) ^ (row & 7)) << 3);
      async_ld16(B + (n0 + row) * K + col, base + j * 8192 + w * 1024);
    }
  };

  f32x4 acc[8][2] = {};
  short8v afA[4][2], afB[4][2], bfA[2][2], bfB[2][2];
  const char* b0 = lds;
  const char* b1 = lds + 49152;

  // prologue: t0 full (6 loads), then t1 B + A-par0 (4 loads)
  stB1(0); stA2(0, 0); stA2(0, 1);
  stB1(1); stA2(1, 0);
  asm volatile("s_waitcnt vmcnt(4)\ns_barrier" ::: "memory");  // tile 0 landed
  RA_READ_A(afA, b0, 0); RA_READ_B(bfA, b0);                   // tile 0 frags (12 ds)

  for (int i = 0; i < NI; ++i) {
    const bool last = (i == NI - 1);
    const int c = 2 * i + 1, e = 2 * i + 2, g = 2 * i + 3;

    // ---- P1: MFMA(tile a=2i, mh0); pre-read a.mh1
    VMBAR(4);                       // stA2(a,1) landed; outstanding: stB1(c)+stA2(c,0)=4
    RA_READ_A(afB, b0, 1);          // 8 ds (a.mh1)
    stA2(c, 1);                     // 2 vm
    LGK(8);                         // afA,bfA landed (only afB outstanding)
    RA_MFMA(afA, bfA, 0);

    // ---- P2: MFMA(a, mh1); pre-read c.mh0 + c.B
    VMBAR(2);                       // stB1(c)+stA2(c,0) landed; outstanding: stA2(c,1)=2
    RA_READ_A(afA, b1, 0);          // 8 ds (c.mh0)
    RA_READ_B(bfB, b1);             // 4 ds (c.B)
    if (!last) { stB1(e); stA2(e, 0); }   // 4 vm
    LGK(12);                        // afB landed (afA+bfB=12 outstanding)
    RA_MFMA(afB, bfA, 1);

    // ---- P3: MFMA(c, mh0); pre-read c.mh1
    if (!last) { VMBAR(4); } else { VMBAR(0); }  // stA2(c,1) landed; outst: stage(e)=4|0
    RA_READ_A(afB, b1, 1);          // 8 ds (c.mh1)
    if (!last) stA2(e, 1);          // 2 vm
    LGK(8);                         // afA,bfB landed
    RA_MFMA(afA, bfB, 0);

    // ---- P4: MFMA(c, mh1); pre-read e.mh0 + e.B
    if (!last) {
      VMBAR(2);                     // stB1(e)+stA2(e,0) landed; outstanding: stA2(e,1)=2
      RA_READ_A(afA, b0, 0);        // 8 ds (e.mh0)
      RA_READ_B(bfA, b0);           // 4 ds (e.B)
      stB1(g); stA2(g, 0);          // 4 vm (g = 2i+3 <= NT-1 here)
      LGK(12);                      // afB landed
    } else {
      LGK(0);                       // final drain
    }
    RA_MFMA(afB, bfB, 1);
  }

  const int colq = l15;
  const int rowq = c16 * 4;
  #pragma unroll
  for (int n = 0; n < 2; ++n) {
    long col = n0 + wc * 32 + n * 16 + colq;
    float bi = bias[col];
    #pragma unroll
    for (int mi = 0; mi < 8; ++mi) {
      long row0 = m0 + wr * 128 + mi * 16 + rowq;
      #pragma unroll
      for (int j = 0; j < 4; ++j) {
        long idx = (row0 + j) * (long)N + col;
        float v = acc[mi][n][j] + bi;
        if (MODE == 0) {
          ((__hip_bfloat16*)outp)[idx] = __float2bfloat16(v);
        } else if (MODE == 1) {
          ((float*)outp)[idx] = v + resid[idx];
        } else {
          float g2 = 0.5f * v * (1.0f + erff(v * 0.70710678118654752f));
          ((__hip_bfloat16*)outp)[idx] = __float2bfloat16(g2);
        }
      }
    }
  }
}

// ---------------------------------------------------------------- causal flash attention (R10-passing)
// qb-paired load balance: grid (8, 32); block bx does q-tiles {15-bx, bx}.
#define QBLK 128
#define KVB  64
#define VSTR 144                      // Vt row stride bytes (72 elems)
#define KBYT 16384                    // K buffer bytes
#define VBYT (DHEAD * VSTR)           // 18432
__global__ __launch_bounds__(256, 2) void attn_kernel(const __hip_bfloat16* __restrict__ qkv,
                                                      __hip_bfloat16* __restrict__ out) {
  __shared__ __align__(16) char smem[2 * KBYT + 2 * VBYT];
  const int tid = threadIdx.x, lane = tid & 63, wid = tid >> 6;
  const int l31 = lane & 31, hi = lane >> 5;
  const int bx = blockIdx.x;
  const int bh = blockIdx.y;
  const int bb = bh >> 4, h = bh & 15;
  const long rowbase = (long)bb * SEQ;
  const int qcol = h * DHEAD, kcol = DMODEL + h * DHEAD, vcol = 2 * DMODEL + h * DHEAD;

  const int kv0s = (tid >> 4) * 4;
  const int dh0s = (tid & 15) * 8;
  auto k_stage = [&](int t) {
    char* kb = smem + (t & 1) * KBYT;
    const long kvr = rowbase + (long)t * KVB;
    #pragma unroll
    for (int i = 0; i < 4; ++i) {
      int c = i * 256 + tid;
      int row = c >> 4, slot = c & 15;
      const void* src = qkv + (kvr + row) * TD + kcol + ((slot ^ (row & 7)) << 3);
      async_ld16(src, kb + i * 4096 + wid * 1024);
    }
  };
  auto v_load = [&](int t, int4* r) {
    const long kvr = rowbase + (long)t * KVB;
    #pragma unroll
    for (int i = 0; i < 4; ++i)
      r[i] = *(const int4*)(qkv + (kvr + kv0s + i) * TD + vcol + dh0s);
  };
  auto v_write = [&](int t, const int4* r) {
    char* vt = smem + 2 * KBYT + (t & 1) * VBYT;
    union { int4 v; unsigned short s[8]; } u0, u1, u2, u3;
    u0.v = r[0]; u1.v = r[1]; u2.v = r[2]; u3.v = r[3];
    #pragma unroll
    for (int dd = 0; dd < 8; ++dd) {
      int d = (dd + ((tid >> 1) & 7)) & 7;
      unsigned lo = (unsigned)u0.s[d] | ((unsigned)u1.s[d] << 16);
      unsigned hi2 = (unsigned)u2.s[d] | ((unsigned)u3.s[d] << 16);
      uint2 wv; wv.x = lo; wv.y = hi2;
      *(uint2*)(vt + (dh0s + d) * VSTR + kv0s * 2) = wv;
    }
  };

  #pragma unroll
  for (int mem = 0; mem < 2; ++mem) {
    const int qb = mem == 0 ? (15 - bx) : bx;   // long member first
    const int q0 = qb * QBLK;
    const int qw0 = q0 + wid * 32;

    short8v qf[8];
    {
      const __hip_bfloat16* qp = qkv + (rowbase + qw0 + l31) * TD + qcol + hi * 8;
      #pragma unroll
      for (int kc = 0; kc < 8; ++kc) qf[kc] = *(const short8v*)(qp + kc * 16);
    }

    f32x16 o[4] = {};
    float m_ = -1e30f, l_ = 0.0f;
    const int nt = (q0 + QBLK) / KVB;

    {
      int4 vr[4];
      v_load(0, vr);
      k_stage(0);
      v_write(0, vr);
    }
    __syncthreads();

    for (int t = 0; t < nt; ++t) {
      int4 vr[4];
      const bool more = (t + 1 < nt);
      if (more) { v_load(t + 1, vr); k_stage(t + 1); }

      const int kv0 = t * KVB;
      if (kv0 <= qw0 + 31) {
        const char* Kb = smem + (t & 1) * KBYT;
        f32x16 s0 = {}, s1 = {};
        #pragma unroll
        for (int kc = 0; kc < 8; ++kc) {
          const int colb = kc * 32 + hi * 16;
          const int r0 = l31, r1 = 32 + l31;
          short8v k0 = *(const short8v*)(Kb + r0 * 256 + (colb ^ ((r0 & 7) << 4)));
          short8v k1 = *(const short8v*)(Kb + r1 * 256 + (colb ^ ((r0 & 7) << 4)));
          s0 = __builtin_amdgcn_mfma_f32_32x32x16_bf16(k0, qf[kc], s0, 0, 0, 0);
          s1 = __builtin_amdgcn_mfma_f32_32x32x16_bf16(k1, qf[kc], s1, 0, 0, 0);
        }
        const float scale = 0.08838834764831845f;
        float sv[32];
        #pragma unroll
        for (int r = 0; r < 16; ++r) { sv[r] = s0[r] * scale; sv[16 + r] = s1[r] * scale; }
        const int qg = qw0 + l31;
        if (kv0 + KVB - 1 > qw0) {
          #pragma unroll
          for (int r = 0; r < 16; ++r) {
            int kvr_ = kv0 + (r & 3) + 8 * (r >> 2) + 4 * hi;
            if (kvr_ > qg)      sv[r]      = -1e30f;
            if (kvr_ + 32 > qg) sv[16 + r] = -1e30f;
          }
        }
        float pmax = sv[0];
        #pragma unroll
        for (int r = 1; r < 32; ++r) pmax = fmaxf(pmax, sv[r]);
        pmax = fmaxf(pmax, __shfl_xor(pmax, 32, 64));
        float mn = fmaxf(m_, pmax);
        float alpha = __expf(m_ - mn);
        m_ = mn;
        l_ *= alpha;
        #pragma unroll
        for (int d = 0; d < 4; ++d)
          #pragma unroll
          for (int r = 0; r < 16; ++r) o[d][r] *= alpha;
        float rsum = 0.0f;
        #pragma unroll
        for (int r = 0; r < 32; ++r) { sv[r] = __expf(sv[r] - m_); rsum += sv[r]; }
        l_ += rsum + __shfl_xor(rsum, 32, 64);
        int pa_[4][4];
        #pragma unroll
        for (int kc = 0; kc < 4; ++kc) {
          int ba = 16 * (kc >> 1) + 8 * (kc & 1);
          unsigned wA0 = pk2(sv[ba + 0], sv[ba + 1]);
          unsigned wA1 = pk2(sv[ba + 2], sv[ba + 3]);
          unsigned wB0 = pk2(sv[ba + 4], sv[ba + 5]);
          unsigned wB1 = pk2(sv[ba + 6], sv[ba + 7]);
          unsigned z0 = (unsigned)__shfl_xor((int)(hi ? wA0 : wB0), 32, 64);
          unsigned z1 = (unsigned)__shfl_xor((int)(hi ? wA1 : wB1), 32, 64);
          pa_[kc][0] = hi ? (int)z0 : (int)wA0;
          pa_[kc][1] = hi ? (int)z1 : (int)wA1;
          pa_[kc][2] = hi ? (int)wB0 : (int)z0;
          pa_[kc][3] = hi ? (int)wB1 : (int)z1;
        }
        const char* Vt = smem + 2 * KBYT + (t & 1) * VBYT;
        #pragma unroll
        for (int dht = 0; dht < 4; ++dht) {
          const int dh = dht * 32 + l31;
          short8v vf[4];
          #pragma unroll
          for (int kc = 0; kc < 4; ++kc)
            vf[kc] = *(const short8v*)(Vt + dh * VSTR + kc * 32 + hi * 16);
          #pragma unroll
          for (int kc = 0; kc < 4; ++kc) {
            union { int i[4]; short8v v; } bv;
            bv.i[0] = pa_[kc][0]; bv.i[1] = pa_[kc][1];
            bv.i[2] = pa_[kc][2]; bv.i[3] = pa_[kc][3];
            o[dht] = __builtin_amdgcn_mfma_f32_32x32x16_bf16(vf[kc], bv.v, o[dht], 0, 0, 0);
          }
        }
      }
      if (more) v_write(t + 1, vr);
      __syncthreads();
    }

    const float linv = 1.0f / l_;
    const long orow = (rowbase + qw0 + l31) * DMODEL + h * DHEAD;
    #pragma unroll
    for (int dht = 0; dht < 4; ++dht)
      #pragma unroll
      for (int rg = 0; rg < 4; ++rg) {
        union { __hip_bfloat16 hh[4]; uint2 u; } pk;
        #pragma unroll
        for (int i = 0; i < 4; ++i) pk.hh[i] = __float2bfloat16(o[dht][rg * 4 + i] * linv);
        *(uint2*)(out + orow + dht * 32 + 8 * rg + 4 * hi) = pk.u;
      }
  }
}

// ---------------------------------------------------------------- launch
extern "C" void kernel_launch(void* const* d_in, const int* in_sizes, int n_in,
                              void* d_out, int out_size, void* d_ws, size_t ws_size,
                              hipStream_t stream) {
  const float* hidden  = (const float*)d_in[0];
  const float* ln1w    = (const float*)d_in[1];
  const float* ln1b    = (const float*)d_in[2];
  const float* qkvw    = (const float*)d_in[3];
  const float* qkvb    = (const float*)d_in[4];
  const float* densew  = (const float*)d_in[5];
  const float* denseb  = (const float*)d_in[6];
  const float* ln2w    = (const float*)d_in[7];
  const float* ln2b    = (const float*)d_in[8];
  const float* fc1w    = (const float*)d_in[9];
  const float* fc1b    = (const float*)d_in[10];
  const float* fc2w    = (const float*)d_in[11];
  const float* fc2b    = (const float*)d_in[12];

  char* ws = (char*)d_ws;
  size_t off = 0;
  auto alloc = [&](size_t bytes) { char* p = ws + off; off += (bytes + 255) & ~(size_t)255; return p; };
  __hip_bfloat16* xbf    = (__hip_bfloat16*)alloc((size_t)TOK * DMODEL * 2);
  __hip_bfloat16* wqkv   = (__hip_bfloat16*)alloc((size_t)TD * DMODEL * 2);
  __hip_bfloat16* wdense = (__hip_bfloat16*)alloc((size_t)DMODEL * DMODEL * 2);
  __hip_bfloat16* wfc1   = (__hip_bfloat16*)alloc((size_t)FFDIM * DMODEL * 2);
  __hip_bfloat16* wfc2   = (__hip_bfloat16*)alloc((size_t)DMODEL * FFDIM * 2);
  __hip_bfloat16* big    = (__hip_bfloat16*)alloc((size_t)TOK * FFDIM * 2);
  float*          x2     = (float*)alloc((size_t)TOK * DMODEL * 4);
  __hip_bfloat16* qkvbuf  = big;
  __hip_bfloat16* attnout = big + (size_t)TOK * TD;
  __hip_bfloat16* gelubuf = big;

  f2bf_kernel<<<1024, 256, 0, stream>>>(qkvw,   wqkv,   (long)TD * DMODEL);
  f2bf_kernel<<<1024, 256, 0, stream>>>(densew, wdense, (long)DMODEL * DMODEL);
  f2bf_kernel<<<1024, 256, 0, stream>>>(fc1w,   wfc1,   (long)FFDIM * DMODEL);
  f2bf_kernel<<<1024, 256, 0, stream>>>(fc2w,   wfc2,   (long)DMODEL * FFDIM);

  ln_kernel<<<TOK, 256, 0, stream>>>(hidden, ln1w, ln1b, xbf);
  gemm128ra<0><<<dim3(TD / 128, TOK / 256), 512, 0, stream>>>(xbf, wqkv, qkvb, nullptr, qkvbuf, TD, DMODEL);
  attn_kernel<<<dim3(8, 2 * NHEAD), 256, 0, stream>>>(qkvbuf, attnout);
  gemm128ra<1><<<dim3(DMODEL / 128, TOK / 256), 512, 0, stream>>>(attnout, wdense, denseb, hidden, x2, DMODEL, DMODEL);
  ln_kernel<<<TOK, 256, 0, stream>>>(x2, ln2w, ln2b, xbf);
  gemm128ra<2><<<dim3(FFDIM / 128, TOK / 256), 512, 0, stream>>>(xbf, wfc1, fc1b, nullptr, gelubuf, FFDIM, DMODEL);
  gemm128ra<1><<<dim3(DMODEL / 128, TOK / 256), 512, 0, stream>>>(gelubuf, wfc2, fc2b, x2, (float*)d_out, DMODEL, FFDIM);
}

// Round 17
// 656.330 us; speedup vs baseline: 1.2127x; 1.0243x over previous
//
#include <hip/hip_runtime.h>
#include <hip/hip_bf16.h>

#define SEQ    2048
#define DMODEL 2048
#define NHEAD  16
#define DHEAD  128
#define TOK    4096   // B*S
#define TD     6144   // 3*D
#define FFDIM  8192

typedef __attribute__((ext_vector_type(4)))  float f32x4;
typedef __attribute__((ext_vector_type(16))) float f32x16;
typedef __attribute__((ext_vector_type(8)))  short short8v;

__device__ __forceinline__ void async_ld16(const void* src, void* lds) {
  __builtin_amdgcn_global_load_lds((const __attribute__((address_space(1))) void*)src,
                                   (__attribute__((address_space(3))) void*)lds, 16, 0, 0);
}

// pack two f32 -> one u32 of 2 bf16, explicit element order (low short = a)
__device__ __forceinline__ unsigned pk2(float a, float b) {
  union { __hip_bfloat16 h[2]; unsigned u; } p;
  p.h[0] = __float2bfloat16(a);
  p.h[1] = __float2bfloat16(b);
  return p.u;
}

// ---------------------------------------------------------------- fp32 -> bf16
__global__ __launch_bounds__(256) void f2bf_kernel(const float* __restrict__ in,
                                                   __hip_bfloat16* __restrict__ out, long n) {
  long i0 = ((long)blockIdx.x * 256 + threadIdx.x) * 8;
  long stride = (long)gridDim.x * 256 * 8;
  for (long i = i0; i < n; i += stride) {
    float4 a = *(const float4*)(in + i);
    float4 b = *(const float4*)(in + i + 4);
    union { __hip_bfloat16 h[8]; int4 v; } p;
    p.h[0] = __float2bfloat16(a.x); p.h[1] = __float2bfloat16(a.y);
    p.h[2] = __float2bfloat16(a.z); p.h[3] = __float2bfloat16(a.w);
    p.h[4] = __float2bfloat16(b.x); p.h[5] = __float2bfloat16(b.y);
    p.h[6] = __float2bfloat16(b.z); p.h[7] = __float2bfloat16(b.w);
    *(int4*)(out + i) = p.v;
  }
}

// ---------------------------------------------------------------- LayerNorm -> bf16
__global__ __launch_bounds__(256) void ln_kernel(const float* __restrict__ x,
                                                 const float* __restrict__ w,
                                                 const float* __restrict__ b,
                                                 __hip_bfloat16* __restrict__ out) {
  __shared__ float red[8];
  const int row = blockIdx.x;
  const int tid = threadIdx.x;
  const float* xr = x + (long)row * DMODEL;
  float4 v0 = ((const float4*)xr)[tid * 2];
  float4 v1 = ((const float4*)xr)[tid * 2 + 1];
  float s  = v0.x + v0.y + v0.z + v0.w + v1.x + v1.y + v1.z + v1.w;
  float ss = v0.x*v0.x + v0.y*v0.y + v0.z*v0.z + v0.w*v0.w
           + v1.x*v1.x + v1.y*v1.y + v1.z*v1.z + v1.w*v1.w;
  #pragma unroll
  for (int m = 1; m < 64; m <<= 1) { s += __shfl_xor(s, m, 64); ss += __shfl_xor(ss, m, 64); }
  if ((tid & 63) == 0) { red[tid >> 6] = s; red[4 + (tid >> 6)] = ss; }
  __syncthreads();
  s  = red[0] + red[1] + red[2] + red[3];
  ss = red[4] + red[5] + red[6] + red[7];
  const float mu = s * (1.0f / DMODEL);
  const float rs = rsqrtf(ss * (1.0f / DMODEL) - mu * mu + 1e-5f);
  float4 w0 = ((const float4*)w)[tid * 2], w1 = ((const float4*)w)[tid * 2 + 1];
  float4 b0 = ((const float4*)b)[tid * 2], b1 = ((const float4*)b)[tid * 2 + 1];
  union { __hip_bfloat16 h[8]; int4 v; } p;
  p.h[0] = __float2bfloat16((v0.x - mu) * rs * w0.x + b0.x);
  p.h[1] = __float2bfloat16((v0.y - mu) * rs * w0.y + b0.y);
  p.h[2] = __float2bfloat16((v0.z - mu) * rs * w0.z + b0.z);
  p.h[3] = __float2bfloat16((v0.w - mu) * rs * w0.w + b0.w);
  p.h[4] = __float2bfloat16((v1.x - mu) * rs * w1.x + b1.x);
  p.h[5] = __float2bfloat16((v1.y - mu) * rs * w1.y + b1.y);
  p.h[6] = __float2bfloat16((v1.z - mu) * rs * w1.z + b1.z);
  p.h[7] = __float2bfloat16((v1.w - mu) * rs * w1.w + b1.w);
  ((int4*)(out + (long)row * DMODEL))[tid] = p.v;
}

// ---------------------------------------------------------------- GEMM macros (R11-verbatim)
#define VMBAR(N) asm volatile("s_waitcnt vmcnt(" #N ")\ns_barrier" ::: "memory")
#define LGK(N)   do { asm volatile("s_waitcnt lgkmcnt(" #N ")" ::: "memory"); \
                      __builtin_amdgcn_sched_barrier(0); } while (0)

#define RA_READ_A(DST, BB, MH) \
  _Pragma("unroll") \
  for (int m = 0; m < 4; ++m) { \
    int row = wr * 128 + (MH) * 64 + m * 16 + l15; \
    _Pragma("unroll") \
    for (int kk = 0; kk < 2; ++kk) \
      DST[m][kk] = *(const short8v*)((BB) + row * 128 + ((((kk << 2) | c16) ^ (row & 7)) << 4)); \
  }
#define RA_READ_B(DST, BB) \
  _Pragma("unroll") \
  for (int n = 0; n < 2; ++n) { \
    int row = wc * 32 + n * 16 + l15; \
    _Pragma("unroll") \
    for (int kk = 0; kk < 2; ++kk) \
      DST[n][kk] = *(const short8v*)((BB) + 32768 + row * 128 + ((((kk << 2) | c16) ^ (row & 7)) << 4)); \
  }
#define RA_MFMA(AF, BF, MH) \
  __builtin_amdgcn_s_setprio(1); \
  _Pragma("unroll") \
  for (int m = 0; m < 4; ++m) \
    _Pragma("unroll") \
    for (int n = 0; n < 2; ++n) \
      _Pragma("unroll") \
      for (int kk = 0; kk < 2; ++kk) \
        acc[(MH) * 4 + m][n] = __builtin_amdgcn_mfma_f32_16x16x32_bf16( \
            AF[m][kk], BF[n][kk], acc[(MH) * 4 + m][n], 0, 0, 0); \
  __builtin_amdgcn_s_setprio(0);

// ---------------------------------------------------------------- 256x128 read-ahead GEMM (all GEMMs)
// R11-VERBATIM (best measured total, 656.9us): 4-phase counted-vmcnt schedule,
// bijective XCD remap. Gates: P1 vm4, P2 vm2, P3 vm4, P4 vm2.
template <int MODE>
__global__ __launch_bounds__(512, 2) void gemm128ra(const __hip_bfloat16* __restrict__ A,
                                                    const __hip_bfloat16* __restrict__ B,
                                                    const float* __restrict__ bias,
                                                    const float* __restrict__ resid,
                                                    void* __restrict__ outp,
                                                    int N, long K) {
  __shared__ __align__(16) char lds[98304];   // 2 x (A 32KB | B 16KB)
  const int tid = threadIdx.x;
  const int lane = tid & 63, w = tid >> 6;
  const int wr = w >> 2, wc = w & 3;
  const int l15 = lane & 15, c16 = lane >> 4;
  // T1: bijective XCD remap (nwg % 8 == 0 for all our grids)
  const int gx = gridDim.x;
  const int nwg = gx * (int)gridDim.y;
  const int lin = (int)blockIdx.y * gx + (int)blockIdx.x;
  const int cpx = nwg >> 3;
  const int swz = (lin & 7) * cpx + (lin >> 3);
  const long m0 = (long)(swz / gx) * 256;
  const long n0 = (long)(swz % gx) * 128;
  const int NT = (int)(K >> 6);
  const int NI = NT >> 1;

  auto stA2 = [&](int t, int par) {           // par 0: quarters {0,2}; 1: {1,3}
    char* base = lds + (t & 1) * 49152;
    #pragma unroll
    for (int j = 0; j < 2; ++j) {
      int q = 2 * j + par;
      int row = q * 64 + (tid >> 3);
      long col = (long)t * 64 + (((tid & 7) ^ (row & 7)) << 3);
      async_ld16(A + (m0 + row) * K + col, base + q * 8192 + w * 1024);
    }
  };
  auto stB1 = [&](int t) {                    // full 128-row B tile (16KB)
    char* base = lds + (t & 1) * 49152 + 32768;
    #pragma unroll
    for (int j = 0; j < 2; ++j) {
      int row = j * 64 + (tid >> 3);
      long col = (long)t * 64 + (((tid & 7) ^ (row & 7)) << 3);
      async_ld16(B + (n0 + row) * K + col, base + j * 8192 + w * 1024);
    }
  };

  f32x4 acc[8][2] = {};
  short8v afA[4][2], afB[4][2], bfA[2][2], bfB[2][2];
  const char* b0 = lds;
  const char* b1 = lds + 49152;

  // prologue: t0 full (6 loads), then t1 B + A-par0 (4 loads)
  stB1(0); stA2(0, 0); stA2(0, 1);
  stB1(1); stA2(1, 0);
  asm volatile("s_waitcnt vmcnt(4)\ns_barrier" ::: "memory");  // tile 0 landed
  RA_READ_A(afA, b0, 0); RA_READ_B(bfA, b0);                   // tile 0 frags (12 ds)

  for (int i = 0; i < NI; ++i) {
    const bool last = (i == NI - 1);
    const int c = 2 * i + 1, e = 2 * i + 2, g = 2 * i + 3;

    // ---- P1: MFMA(tile a=2i, mh0); pre-read a.mh1
    VMBAR(4);                       // stA2(a,1) landed; outstanding: stB1(c)+stA2(c,0)=4
    RA_READ_A(afB, b0, 1);          // 8 ds (a.mh1)
    stA2(c, 1);                     // 2 vm
    LGK(8);                         // afA,bfA landed (only afB outstanding)
    RA_MFMA(afA, bfA, 0);

    // ---- P2: MFMA(a, mh1); pre-read c.mh0 + c.B
    VMBAR(2);                       // stB1(c)+stA2(c,0) landed; outstanding: stA2(c,1)=2
    RA_READ_A(afA, b1, 0);          // 8 ds (c.mh0)
    RA_READ_B(bfB, b1);             // 4 ds (c.B)
    if (!last) { stB1(e); stA2(e, 0); }   // 4 vm
    LGK(12);                        // afB landed (afA+bfB=12 outstanding)
    RA_MFMA(afB, bfA, 1);

    // ---- P3: MFMA(c, mh0); pre-read c.mh1
    if (!last) { VMBAR(4); } else { VMBAR(0); }  // stA2(c,1) landed; outst: stage(e)=4|0
    RA_READ_A(afB, b1, 1);          // 8 ds (c.mh1)
    if (!last) stA2(e, 1);          // 2 vm
    LGK(8);                         // afA,bfB landed
    RA_MFMA(afA, bfB, 0);

    // ---- P4: MFMA(c, mh1); pre-read e.mh0 + e.B
    if (!last) {
      VMBAR(2);                     // stB1(e)+stA2(e,0) landed; outstanding: stA2(e,1)=2
      RA_READ_A(afA, b0, 0);        // 8 ds (e.mh0)
      RA_READ_B(bfA, b0);           // 4 ds (e.B)
      stB1(g); stA2(g, 0);          // 4 vm (g = 2i+3 <= NT-1 here)
      LGK(12);                      // afB landed
    } else {
      LGK(0);                       // final drain
    }
    RA_MFMA(afB, bfB, 1);
  }

  const int colq = l15;
  const int rowq = c16 * 4;
  #pragma unroll
  for (int n = 0; n < 2; ++n) {
    long col = n0 + wc * 32 + n * 16 + colq;
    float bi = bias[col];
    #pragma unroll
    for (int mi = 0; mi < 8; ++mi) {
      long row0 = m0 + wr * 128 + mi * 16 + rowq;
      #pragma unroll
      for (int j = 0; j < 4; ++j) {
        long idx = (row0 + j) * (long)N + col;
        float v = acc[mi][n][j] + bi;
        if (MODE == 0) {
          ((__hip_bfloat16*)outp)[idx] = __float2bfloat16(v);
        } else if (MODE == 1) {
          ((float*)outp)[idx] = v + resid[idx];
        } else {
          float g2 = 0.5f * v * (1.0f + erff(v * 0.70710678118654752f));
          ((__hip_bfloat16*)outp)[idx] = __float2bfloat16(g2);
        }
      }
    }
  }
}

// ---------------------------------------------------------------- causal flash attention (R10-passing)
// qb-paired load balance: grid (8, 32); block bx does q-tiles {15-bx, bx}.
#define QBLK 128
#define KVB  64
#define VSTR 144                      // Vt row stride bytes (72 elems)
#define KBYT 16384                    // K buffer bytes
#define VBYT (DHEAD * VSTR)           // 18432
__global__ __launch_bounds__(256, 2) void attn_kernel(const __hip_bfloat16* __restrict__ qkv,
                                                      __hip_bfloat16* __restrict__ out) {
  __shared__ __align__(16) char smem[2 * KBYT + 2 * VBYT];
  const int tid = threadIdx.x, lane = tid & 63, wid = tid >> 6;
  const int l31 = lane & 31, hi = lane >> 5;
  const int bx = blockIdx.x;
  const int bh = blockIdx.y;
  const int bb = bh >> 4, h = bh & 15;
  const long rowbase = (long)bb * SEQ;
  const int qcol = h * DHEAD, kcol = DMODEL + h * DHEAD, vcol = 2 * DMODEL + h * DHEAD;

  const int kv0s = (tid >> 4) * 4;
  const int dh0s = (tid & 15) * 8;
  auto k_stage = [&](int t) {
    char* kb = smem + (t & 1) * KBYT;
    const long kvr = rowbase + (long)t * KVB;
    #pragma unroll
    for (int i = 0; i < 4; ++i) {
      int c = i * 256 + tid;
      int row = c >> 4, slot = c & 15;
      const void* src = qkv + (kvr + row) * TD + kcol + ((slot ^ (row & 7)) << 3);
      async_ld16(src, kb + i * 4096 + wid * 1024);
    }
  };
  auto v_load = [&](int t, int4* r) {
    const long kvr = rowbase + (long)t * KVB;
    #pragma unroll
    for (int i = 0; i < 4; ++i)
      r[i] = *(const int4*)(qkv + (kvr + kv0s + i) * TD + vcol + dh0s);
  };
  auto v_write = [&](int t, const int4* r) {
    char* vt = smem + 2 * KBYT + (t & 1) * VBYT;
    union { int4 v; unsigned short s[8]; } u0, u1, u2, u3;
    u0.v = r[0]; u1.v = r[1]; u2.v = r[2]; u3.v = r[3];
    #pragma unroll
    for (int dd = 0; dd < 8; ++dd) {
      int d = (dd + ((tid >> 1) & 7)) & 7;
      unsigned lo = (unsigned)u0.s[d] | ((unsigned)u1.s[d] << 16);
      unsigned hi2 = (unsigned)u2.s[d] | ((unsigned)u3.s[d] << 16);
      uint2 wv; wv.x = lo; wv.y = hi2;
      *(uint2*)(vt + (dh0s + d) * VSTR + kv0s * 2) = wv;
    }
  };

  #pragma unroll
  for (int mem = 0; mem < 2; ++mem) {
    const int qb = mem == 0 ? (15 - bx) : bx;   // long member first
    const int q0 = qb * QBLK;
    const int qw0 = q0 + wid * 32;

    short8v qf[8];
    {
      const __hip_bfloat16* qp = qkv + (rowbase + qw0 + l31) * TD + qcol + hi * 8;
      #pragma unroll
      for (int kc = 0; kc < 8; ++kc) qf[kc] = *(const short8v*)(qp + kc * 16);
    }

    f32x16 o[4] = {};
    float m_ = -1e30f, l_ = 0.0f;
    const int nt = (q0 + QBLK) / KVB;

    {
      int4 vr[4];
      v_load(0, vr);
      k_stage(0);
      v_write(0, vr);
    }
    __syncthreads();

    for (int t = 0; t < nt; ++t) {
      int4 vr[4];
      const bool more = (t + 1 < nt);
      if (more) { v_load(t + 1, vr); k_stage(t + 1); }

      const int kv0 = t * KVB;
      if (kv0 <= qw0 + 31) {
        const char* Kb = smem + (t & 1) * KBYT;
        f32x16 s0 = {}, s1 = {};
        #pragma unroll
        for (int kc = 0; kc < 8; ++kc) {
          const int colb = kc * 32 + hi * 16;
          const int r0 = l31, r1 = 32 + l31;
          short8v k0 = *(const short8v*)(Kb + r0 * 256 + (colb ^ ((r0 & 7) << 4)));
          short8v k1 = *(const short8v*)(Kb + r1 * 256 + (colb ^ ((r0 & 7) << 4)));
          s0 = __builtin_amdgcn_mfma_f32_32x32x16_bf16(k0, qf[kc], s0, 0, 0, 0);
          s1 = __builtin_amdgcn_mfma_f32_32x32x16_bf16(k1, qf[kc], s1, 0, 0, 0);
        }
        const float scale = 0.08838834764831845f;
        float sv[32];
        #pragma unroll
        for (int r = 0; r < 16; ++r) { sv[r] = s0[r] * scale; sv[16 + r] = s1[r] * scale; }
        const int qg = qw0 + l31;
        if (kv0 + KVB - 1 > qw0) {
          #pragma unroll
          for (int r = 0; r < 16; ++r) {
            int kvr_ = kv0 + (r & 3) + 8 * (r >> 2) + 4 * hi;
            if (kvr_ > qg)      sv[r]      = -1e30f;
            if (kvr_ + 32 > qg) sv[16 + r] = -1e30f;
          }
        }
        float pmax = sv[0];
        #pragma unroll
        for (int r = 1; r < 32; ++r) pmax = fmaxf(pmax, sv[r]);
        pmax = fmaxf(pmax, __shfl_xor(pmax, 32, 64));
        float mn = fmaxf(m_, pmax);
        float alpha = __expf(m_ - mn);
        m_ = mn;
        l_ *= alpha;
        #pragma unroll
        for (int d = 0; d < 4; ++d)
          #pragma unroll
          for (int r = 0; r < 16; ++r) o[d][r] *= alpha;
        float rsum = 0.0f;
        #pragma unroll
        for (int r = 0; r < 32; ++r) { sv[r] = __expf(sv[r] - m_); rsum += sv[r]; }
        l_ += rsum + __shfl_xor(rsum, 32, 64);
        int pa_[4][4];
        #pragma unroll
        for (int kc = 0; kc < 4; ++kc) {
          int ba = 16 * (kc >> 1) + 8 * (kc & 1);
          unsigned wA0 = pk2(sv[ba + 0], sv[ba + 1]);
          unsigned wA1 = pk2(sv[ba + 2], sv[ba + 3]);
          unsigned wB0 = pk2(sv[ba + 4], sv[ba + 5]);
          unsigned wB1 = pk2(sv[ba + 6], sv[ba + 7]);
          unsigned z0 = (unsigned)__shfl_xor((int)(hi ? wA0 : wB0), 32, 64);
          unsigned z1 = (unsigned)__shfl_xor((int)(hi ? wA1 : wB1), 32, 64);
          pa_[kc][0] = hi ? (int)z0 : (int)wA0;
          pa_[kc][1] = hi ? (int)z1 : (int)wA1;
          pa_[kc][2] = hi ? (int)wB0 : (int)z0;
          pa_[kc][3] = hi ? (int)wB1 : (int)z1;
        }
        const char* Vt = smem + 2 * KBYT + (t & 1) * VBYT;
        #pragma unroll
        for (int dht = 0; dht < 4; ++dht) {
          const int dh = dht * 32 + l31;
          short8v vf[4];
          #pragma unroll
          for (int kc = 0; kc < 4; ++kc)
            vf[kc] = *(const short8v*)(Vt + dh * VSTR + kc * 32 + hi * 16);
          #pragma unroll
          for (int kc = 0; kc < 4; ++kc) {
            union { int i[4]; short8v v; } bv;
            bv.i[0] = pa_[kc][0]; bv.i[1] = pa_[kc][1];
            bv.i[2] = pa_[kc][2]; bv.i[3] = pa_[kc][3];
            o[dht] = __builtin_amdgcn_mfma_f32_32x32x16_bf16(vf[kc], bv.v, o[dht], 0, 0, 0);
          }
        }
      }
      if (more) v_write(t + 1, vr);
      __syncthreads();
    }

    const float linv = 1.0f / l_;
    const long orow = (rowbase + qw0 + l31) * DMODEL + h * DHEAD;
    #pragma unroll
    for (int dht = 0; dht < 4; ++dht)
      #pragma unroll
      for (int rg = 0; rg < 4; ++rg) {
        union { __hip_bfloat16 hh[4]; uint2 u; } pk;
        #pragma unroll
        for (int i = 0; i < 4; ++i) pk.hh[i] = __float2bfloat16(o[dht][rg * 4 + i] * linv);
        *(uint2*)(out + orow + dht * 32 + 8 * rg + 4 * hi) = pk.u;
      }
  }
}

// ---------------------------------------------------------------- launch
extern "C" void kernel_launch(void* const* d_in, const int* in_sizes, int n_in,
                              void* d_out, int out_size, void* d_ws, size_t ws_size,
                              hipStream_t stream) {
  const float* hidden  = (const float*)d_in[0];
  const float* ln1w    = (const float*)d_in[1];
  const float* ln1b    = (const float*)d_in[2];
  const float* qkvw    = (const float*)d_in[3];
  const float* qkvb    = (const float*)d_in[4];
  const float* densew  = (const float*)d_in[5];
  const float* denseb  = (const float*)d_in[6];
  const float* ln2w    = (const float*)d_in[7];
  const float* ln2b    = (const float*)d_in[8];
  const float* fc1w    = (const float*)d_in[9];
  const float* fc1b    = (const float*)d_in[10];
  const float* fc2w    = (const float*)d_in[11];
  const float* fc2b    = (const float*)d_in[12];

  char* ws = (char*)d_ws;
  size_t off = 0;
  auto alloc = [&](size_t bytes) { char* p = ws + off; off += (bytes + 255) & ~(size_t)255; return p; };
  __hip_bfloat16* xbf    = (__hip_bfloat16*)alloc((size_t)TOK * DMODEL * 2);
  __hip_bfloat16* wqkv   = (__hip_bfloat16*)alloc((size_t)TD * DMODEL * 2);
  __hip_bfloat16* wdense = (__hip_bfloat16*)alloc((size_t)DMODEL * DMODEL * 2);
  __hip_bfloat16* wfc1   = (__hip_bfloat16*)alloc((size_t)FFDIM * DMODEL * 2);
  __hip_bfloat16* wfc2   = (__hip_bfloat16*)alloc((size_t)DMODEL * FFDIM * 2);
  __hip_bfloat16* big    = (__hip_bfloat16*)alloc((size_t)TOK * FFDIM * 2);
  float*          x2     = (float*)alloc((size_t)TOK * DMODEL * 4);
  __hip_bfloat16* qkvbuf  = big;
  __hip_bfloat16* attnout = big + (size_t)TOK * TD;
  __hip_bfloat16* gelubuf = big;

  f2bf_kernel<<<1024, 256, 0, stream>>>(qkvw,   wqkv,   (long)TD * DMODEL);
  f2bf_kernel<<<1024, 256, 0, stream>>>(densew, wdense, (long)DMODEL * DMODEL);
  f2bf_kernel<<<1024, 256, 0, stream>>>(fc1w,   wfc1,   (long)FFDIM * DMODEL);
  f2bf_kernel<<<1024, 256, 0, stream>>>(fc2w,   wfc2,   (long)DMODEL * FFDIM);

  ln_kernel<<<TOK, 256, 0, stream>>>(hidden, ln1w, ln1b, xbf);
  gemm128ra<0><<<dim3(TD / 128, TOK / 256), 512, 0, stream>>>(xbf, wqkv, qkvb, nullptr, qkvbuf, TD, DMODEL);
  attn_kernel<<<dim3(8, 2 * NHEAD), 256, 0, stream>>>(qkvbuf, attnout);
  gemm128ra<1><<<dim3(DMODEL / 128, TOK / 256), 512, 0, stream>>>(attnout, wdense, denseb, hidden, x2, DMODEL, DMODEL);
  ln_kernel<<<TOK, 256, 0, stream>>>(x2, ln2w, ln2b, xbf);
  gemm128ra<2><<<dim3(FFDIM / 128, TOK / 256), 512, 0, stream>>>(xbf, wfc1, fc1b, nullptr, gelubuf, FFDIM, DMODEL);
  gemm128ra<1><<<dim3(DMODEL / 128, TOK / 256), 512, 0, stream>>>(gelubuf, wfc2, fc2b, x2, (float*)d_out, DMODEL, FFDIM);
}

// Round 18
// 649.144 us; speedup vs baseline: 1.2261x; 1.0111x over previous
//
#include <hip/hip_runtime.h>
#include <hip/hip_bf16.h>

#define SEQ    2048
#define DMODEL 2048
#define NHEAD  16
#define DHEAD  128
#define TOK    4096   // B*S
#define TD     6144   // 3*D
#define FFDIM  8192

typedef __attribute__((ext_vector_type(4)))  float f32x4;
typedef __attribute__((ext_vector_type(16))) float f32x16;
typedef __attribute__((ext_vector_type(8)))  short short8v;

__device__ __forceinline__ void async_ld16(const void* src, void* lds) {
  __builtin_amdgcn_global_load_lds((const __attribute__((address_space(1))) void*)src,
                                   (__attribute__((address_space(3))) void*)lds, 16, 0, 0);
}

// pack two f32 -> one u32 of 2 bf16, explicit element order (low short = a)
__device__ __forceinline__ unsigned pk2(float a, float b) {
  union { __hip_bfloat16 h[2]; unsigned u; } p;
  p.h[0] = __float2bfloat16(a);
  p.h[1] = __float2bfloat16(b);
  return p.u;
}

// ---------------------------------------------------------------- batched fp32 -> bf16 (4 segments, 1 launch)
__global__ __launch_bounds__(256) void f2bf4_kernel(const float* __restrict__ s0, __hip_bfloat16* __restrict__ d0, long n0,
                                                    const float* __restrict__ s1, __hip_bfloat16* __restrict__ d1, long n1,
                                                    const float* __restrict__ s2, __hip_bfloat16* __restrict__ d2, long n2,
                                                    const float* __restrict__ s3, __hip_bfloat16* __restrict__ d3, long n3) {
  const long total = n0 + n1 + n2 + n3;
  long i0 = ((long)blockIdx.x * 256 + threadIdx.x) * 8;
  long stride = (long)gridDim.x * 256 * 8;
  for (long i = i0; i < total; i += stride) {
    const float* src; __hip_bfloat16* dst; long off;
    if (i < n0)                { src = s0; dst = d0; off = i; }
    else if (i < n0 + n1)      { src = s1; dst = d1; off = i - n0; }
    else if (i < n0 + n1 + n2) { src = s2; dst = d2; off = i - n0 - n1; }
    else                       { src = s3; dst = d3; off = i - n0 - n1 - n2; }
    float4 a = *(const float4*)(src + off);
    float4 b = *(const float4*)(src + off + 4);
    union { __hip_bfloat16 h[8]; int4 v; } p;
    p.h[0] = __float2bfloat16(a.x); p.h[1] = __float2bfloat16(a.y);
    p.h[2] = __float2bfloat16(a.z); p.h[3] = __float2bfloat16(a.w);
    p.h[4] = __float2bfloat16(b.x); p.h[5] = __float2bfloat16(b.y);
    p.h[6] = __float2bfloat16(b.z); p.h[7] = __float2bfloat16(b.w);
    *(int4*)(dst + off) = p.v;
  }
}

// ---------------------------------------------------------------- LayerNorm -> bf16
__global__ __launch_bounds__(256) void ln_kernel(const float* __restrict__ x,
                                                 const float* __restrict__ w,
                                                 const float* __restrict__ b,
                                                 __hip_bfloat16* __restrict__ out) {
  __shared__ float red[8];
  const int row = blockIdx.x;
  const int tid = threadIdx.x;
  const float* xr = x + (long)row * DMODEL;
  float4 v0 = ((const float4*)xr)[tid * 2];
  float4 v1 = ((const float4*)xr)[tid * 2 + 1];
  float s  = v0.x + v0.y + v0.z + v0.w + v1.x + v1.y + v1.z + v1.w;
  float ss = v0.x*v0.x + v0.y*v0.y + v0.z*v0.z + v0.w*v0.w
           + v1.x*v1.x + v1.y*v1.y + v1.z*v1.z + v1.w*v1.w;
  #pragma unroll
  for (int m = 1; m < 64; m <<= 1) { s += __shfl_xor(s, m, 64); ss += __shfl_xor(ss, m, 64); }
  if ((tid & 63) == 0) { red[tid >> 6] = s; red[4 + (tid >> 6)] = ss; }
  __syncthreads();
  s  = red[0] + red[1] + red[2] + red[3];
  ss = red[4] + red[5] + red[6] + red[7];
  const float mu = s * (1.0f / DMODEL);
  const float rs = rsqrtf(ss * (1.0f / DMODEL) - mu * mu + 1e-5f);
  float4 w0 = ((const float4*)w)[tid * 2], w1 = ((const float4*)w)[tid * 2 + 1];
  float4 b0 = ((const float4*)b)[tid * 2], b1 = ((const float4*)b)[tid * 2 + 1];
  union { __hip_bfloat16 h[8]; int4 v; } p;
  p.h[0] = __float2bfloat16((v0.x - mu) * rs * w0.x + b0.x);
  p.h[1] = __float2bfloat16((v0.y - mu) * rs * w0.y + b0.y);
  p.h[2] = __float2bfloat16((v0.z - mu) * rs * w0.z + b0.z);
  p.h[3] = __float2bfloat16((v0.w - mu) * rs * w0.w + b0.w);
  p.h[4] = __float2bfloat16((v1.x - mu) * rs * w1.x + b1.x);
  p.h[5] = __float2bfloat16((v1.y - mu) * rs * w1.y + b1.y);
  p.h[6] = __float2bfloat16((v1.z - mu) * rs * w1.z + b1.z);
  p.h[7] = __float2bfloat16((v1.w - mu) * rs * w1.w + b1.w);
  ((int4*)(out + (long)row * DMODEL))[tid] = p.v;
}

// ---------------------------------------------------------------- GEMM macros (R11-verbatim)
#define VMBAR(N) asm volatile("s_waitcnt vmcnt(" #N ")\ns_barrier" ::: "memory")
#define LGK(N)   do { asm volatile("s_waitcnt lgkmcnt(" #N ")" ::: "memory"); \
                      __builtin_amdgcn_sched_barrier(0); } while (0)

#define RA_READ_A(DST, BB, MH) \
  _Pragma("unroll") \
  for (int m = 0; m < 4; ++m) { \
    int row = wr * 128 + (MH) * 64 + m * 16 + l15; \
    _Pragma("unroll") \
    for (int kk = 0; kk < 2; ++kk) \
      DST[m][kk] = *(const short8v*)((BB) + row * 128 + ((((kk << 2) | c16) ^ (row & 7)) << 4)); \
  }
#define RA_READ_B(DST, BB) \
  _Pragma("unroll") \
  for (int n = 0; n < 2; ++n) { \
    int row = wc * 32 + n * 16 + l15; \
    _Pragma("unroll") \
    for (int kk = 0; kk < 2; ++kk) \
      DST[n][kk] = *(const short8v*)((BB) + 32768 + row * 128 + ((((kk << 2) | c16) ^ (row & 7)) << 4)); \
  }
#define RA_MFMA(AF, BF, MH) \
  __builtin_amdgcn_s_setprio(1); \
  _Pragma("unroll") \
  for (int m = 0; m < 4; ++m) \
    _Pragma("unroll") \
    for (int n = 0; n < 2; ++n) \
      _Pragma("unroll") \
      for (int kk = 0; kk < 2; ++kk) \
        acc[(MH) * 4 + m][n] = __builtin_amdgcn_mfma_f32_16x16x32_bf16( \
            AF[m][kk], BF[n][kk], acc[(MH) * 4 + m][n], 0, 0, 0); \
  __builtin_amdgcn_s_setprio(0);

// ---------------------------------------------------------------- 256x128 read-ahead GEMM (all GEMMs)
// R11-VERBATIM (best measured, reproduced 656.9/656.3us): 4-phase counted-vmcnt
// schedule, bijective XCD remap. Gates: P1 vm4, P2 vm2, P3 vm4, P4 vm2.
template <int MODE>
__global__ __launch_bounds__(512, 2) void gemm128ra(const __hip_bfloat16* __restrict__ A,
                                                    const __hip_bfloat16* __restrict__ B,
                                                    const float* __restrict__ bias,
                                                    const float* __restrict__ resid,
                                                    void* __restrict__ outp,
                                                    int N, long K) {
  __shared__ __align__(16) char lds[98304];   // 2 x (A 32KB | B 16KB)
  const int tid = threadIdx.x;
  const int lane = tid & 63, w = tid >> 6;
  const int wr = w >> 2, wc = w & 3;
  const int l15 = lane & 15, c16 = lane >> 4;
  // T1: bijective XCD remap (nwg % 8 == 0 for all our grids)
  const int gx = gridDim.x;
  const int nwg = gx * (int)gridDim.y;
  const int lin = (int)blockIdx.y * gx + (int)blockIdx.x;
  const int cpx = nwg >> 3;
  const int swz = (lin & 7) * cpx + (lin >> 3);
  const long m0 = (long)(swz / gx) * 256;
  const long n0 = (long)(swz % gx) * 128;
  const int NT = (int)(K >> 6);
  const int NI = NT >> 1;

  auto stA2 = [&](int t, int par) {           // par 0: quarters {0,2}; 1: {1,3}
    char* base = lds + (t & 1) * 49152;
    #pragma unroll
    for (int j = 0; j < 2; ++j) {
      int q = 2 * j + par;
      int row = q * 64 + (tid >> 3);
      long col = (long)t * 64 + (((tid & 7) ^ (row & 7)) << 3);
      async_ld16(A + (m0 + row) * K + col, base + q * 8192 + w * 1024);
    }
  };
  auto stB1 = [&](int t) {                    // full 128-row B tile (16KB)
    char* base = lds + (t & 1) * 49152 + 32768;
    #pragma unroll
    for (int j = 0; j < 2; ++j) {
      int row = j * 64 + (tid >> 3);
      long col = (long)t * 64 + (((tid & 7) ^ (row & 7)) << 3);
      async_ld16(B + (n0 + row) * K + col, base + j * 8192 + w * 1024);
    }
  };

  f32x4 acc[8][2] = {};
  short8v afA[4][2], afB[4][2], bfA[2][2], bfB[2][2];
  const char* b0 = lds;
  const char* b1 = lds + 49152;

  // prologue: t0 full (6 loads), then t1 B + A-par0 (4 loads)
  stB1(0); stA2(0, 0); stA2(0, 1);
  stB1(1); stA2(1, 0);
  asm volatile("s_waitcnt vmcnt(4)\ns_barrier" ::: "memory");  // tile 0 landed
  RA_READ_A(afA, b0, 0); RA_READ_B(bfA, b0);                   // tile 0 frags (12 ds)

  for (int i = 0; i < NI; ++i) {
    const bool last = (i == NI - 1);
    const int c = 2 * i + 1, e = 2 * i + 2, g = 2 * i + 3;

    // ---- P1: MFMA(tile a=2i, mh0); pre-read a.mh1
    VMBAR(4);                       // stA2(a,1) landed; outstanding: stB1(c)+stA2(c,0)=4
    RA_READ_A(afB, b0, 1);          // 8 ds (a.mh1)
    stA2(c, 1);                     // 2 vm
    LGK(8);                         // afA,bfA landed (only afB outstanding)
    RA_MFMA(afA, bfA, 0);

    // ---- P2: MFMA(a, mh1); pre-read c.mh0 + c.B
    VMBAR(2);                       // stB1(c)+stA2(c,0) landed; outstanding: stA2(c,1)=2
    RA_READ_A(afA, b1, 0);          // 8 ds (c.mh0)
    RA_READ_B(bfB, b1);             // 4 ds (c.B)
    if (!last) { stB1(e); stA2(e, 0); }   // 4 vm
    LGK(12);                        // afB landed (afA+bfB=12 outstanding)
    RA_MFMA(afB, bfA, 1);

    // ---- P3: MFMA(c, mh0); pre-read c.mh1
    if (!last) { VMBAR(4); } else { VMBAR(0); }  // stA2(c,1) landed; outst: stage(e)=4|0
    RA_READ_A(afB, b1, 1);          // 8 ds (c.mh1)
    if (!last) stA2(e, 1);          // 2 vm
    LGK(8);                         // afA,bfB landed
    RA_MFMA(afA, bfB, 0);

    // ---- P4: MFMA(c, mh1); pre-read e.mh0 + e.B
    if (!last) {
      VMBAR(2);                     // stB1(e)+stA2(e,0) landed; outstanding: stA2(e,1)=2
      RA_READ_A(afA, b0, 0);        // 8 ds (e.mh0)
      RA_READ_B(bfA, b0);           // 4 ds (e.B)
      stB1(g); stA2(g, 0);          // 4 vm (g = 2i+3 <= NT-1 here)
      LGK(12);                      // afB landed
    } else {
      LGK(0);                       // final drain
    }
    RA_MFMA(afB, bfB, 1);
  }

  const int colq = l15;
  const int rowq = c16 * 4;
  #pragma unroll
  for (int n = 0; n < 2; ++n) {
    long col = n0 + wc * 32 + n * 16 + colq;
    float bi = bias[col];
    #pragma unroll
    for (int mi = 0; mi < 8; ++mi) {
      long row0 = m0 + wr * 128 + mi * 16 + rowq;
      #pragma unroll
      for (int j = 0; j < 4; ++j) {
        long idx = (row0 + j) * (long)N + col;
        float v = acc[mi][n][j] + bi;
        if (MODE == 0) {
          ((__hip_bfloat16*)outp)[idx] = __float2bfloat16(v);
        } else if (MODE == 1) {
          ((float*)outp)[idx] = v + resid[idx];
        } else {
          float g2 = 0.5f * v * (1.0f + erff(v * 0.70710678118654752f));
          ((__hip_bfloat16*)outp)[idx] = __float2bfloat16(g2);
        }
      }
    }
  }
}

// ---------------------------------------------------------------- causal flash attention (R10-passing)
// qb-paired load balance: grid (8, 32); block bx does q-tiles {15-bx, bx}.
#define QBLK 128
#define KVB  64
#define VSTR 144                      // Vt row stride bytes (72 elems)
#define KBYT 16384                    // K buffer bytes
#define VBYT (DHEAD * VSTR)           // 18432
__global__ __launch_bounds__(256, 2) void attn_kernel(const __hip_bfloat16* __restrict__ qkv,
                                                      __hip_bfloat16* __restrict__ out) {
  __shared__ __align__(16) char smem[2 * KBYT + 2 * VBYT];
  const int tid = threadIdx.x, lane = tid & 63, wid = tid >> 6;
  const int l31 = lane & 31, hi = lane >> 5;
  const int bx = blockIdx.x;
  const int bh = blockIdx.y;
  const int bb = bh >> 4, h = bh & 15;
  const long rowbase = (long)bb * SEQ;
  const int qcol = h * DHEAD, kcol = DMODEL + h * DHEAD, vcol = 2 * DMODEL + h * DHEAD;

  const int kv0s = (tid >> 4) * 4;
  const int dh0s = (tid & 15) * 8;
  auto k_stage = [&](int t) {
    char* kb = smem + (t & 1) * KBYT;
    const long kvr = rowbase + (long)t * KVB;
    #pragma unroll
    for (int i = 0; i < 4; ++i) {
      int c = i * 256 + tid;
      int row = c >> 4, slot = c & 15;
      const void* src = qkv + (kvr + row) * TD + kcol + ((slot ^ (row & 7)) << 3);
      async_ld16(src, kb + i * 4096 + wid * 1024);
    }
  };
  auto v_load = [&](int t, int4* r) {
    const long kvr = rowbase + (long)t * KVB;
    #pragma unroll
    for (int i = 0; i < 4; ++i)
      r[i] = *(const int4*)(qkv + (kvr + kv0s + i) * TD + vcol + dh0s);
  };
  auto v_write = [&](int t, const int4* r) {
    char* vt = smem + 2 * KBYT + (t & 1) * VBYT;
    union { int4 v; unsigned short s[8]; } u0, u1, u2, u3;
    u0.v = r[0]; u1.v = r[1]; u2.v = r[2]; u3.v = r[3];
    #pragma unroll
    for (int dd = 0; dd < 8; ++dd) {
      int d = (dd + ((tid >> 1) & 7)) & 7;
      unsigned lo = (unsigned)u0.s[d] | ((unsigned)u1.s[d] << 16);
      unsigned hi2 = (unsigned)u2.s[d] | ((unsigned)u3.s[d] << 16);
      uint2 wv; wv.x = lo; wv.y = hi2;
      *(uint2*)(vt + (dh0s + d) * VSTR + kv0s * 2) = wv;
    }
  };

  #pragma unroll
  for (int mem = 0; mem < 2; ++mem) {
    const int qb = mem == 0 ? (15 - bx) : bx;   // long member first
    const int q0 = qb * QBLK;
    const int qw0 = q0 + wid * 32;

    short8v qf[8];
    {
      const __hip_bfloat16* qp = qkv + (rowbase + qw0 + l31) * TD + qcol + hi * 8;
      #pragma unroll
      for (int kc = 0; kc < 8; ++kc) qf[kc] = *(const short8v*)(qp + kc * 16);
    }

    f32x16 o[4] = {};
    float m_ = -1e30f, l_ = 0.0f;
    const int nt = (q0 + QBLK) / KVB;

    {
      int4 vr[4];
      v_load(0, vr);
      k_stage(0);
      v_write(0, vr);
    }
    __syncthreads();

    for (int t = 0; t < nt; ++t) {
      int4 vr[4];
      const bool more = (t + 1 < nt);
      if (more) { v_load(t + 1, vr); k_stage(t + 1); }

      const int kv0 = t * KVB;
      if (kv0 <= qw0 + 31) {
        const char* Kb = smem + (t & 1) * KBYT;
        f32x16 s0 = {}, s1 = {};
        #pragma unroll
        for (int kc = 0; kc < 8; ++kc) {
          const int colb = kc * 32 + hi * 16;
          const int r0 = l31, r1 = 32 + l31;
          short8v k0 = *(const short8v*)(Kb + r0 * 256 + (colb ^ ((r0 & 7) << 4)));
          short8v k1 = *(const short8v*)(Kb + r1 * 256 + (colb ^ ((r0 & 7) << 4)));
          s0 = __builtin_amdgcn_mfma_f32_32x32x16_bf16(k0, qf[kc], s0, 0, 0, 0);
          s1 = __builtin_amdgcn_mfma_f32_32x32x16_bf16(k1, qf[kc], s1, 0, 0, 0);
        }
        const float scale = 0.08838834764831845f;
        float sv[32];
        #pragma unroll
        for (int r = 0; r < 16; ++r) { sv[r] = s0[r] * scale; sv[16 + r] = s1[r] * scale; }
        const int qg = qw0 + l31;
        if (kv0 + KVB - 1 > qw0) {
          #pragma unroll
          for (int r = 0; r < 16; ++r) {
            int kvr_ = kv0 + (r & 3) + 8 * (r >> 2) + 4 * hi;
            if (kvr_ > qg)      sv[r]      = -1e30f;
            if (kvr_ + 32 > qg) sv[16 + r] = -1e30f;
          }
        }
        float pmax = sv[0];
        #pragma unroll
        for (int r = 1; r < 32; ++r) pmax = fmaxf(pmax, sv[r]);
        pmax = fmaxf(pmax, __shfl_xor(pmax, 32, 64));
        float mn = fmaxf(m_, pmax);
        float alpha = __expf(m_ - mn);
        m_ = mn;
        l_ *= alpha;
        #pragma unroll
        for (int d = 0; d < 4; ++d)
          #pragma unroll
          for (int r = 0; r < 16; ++r) o[d][r] *= alpha;
        float rsum = 0.0f;
        #pragma unroll
        for (int r = 0; r < 32; ++r) { sv[r] = __expf(sv[r] - m_); rsum += sv[r]; }
        l_ += rsum + __shfl_xor(rsum, 32, 64);
        int pa_[4][4];
        #pragma unroll
        for (int kc = 0; kc < 4; ++kc) {
          int ba = 16 * (kc >> 1) + 8 * (kc & 1);
          unsigned wA0 = pk2(sv[ba + 0], sv[ba + 1]);
          unsigned wA1 = pk2(sv[ba + 2], sv[ba + 3]);
          unsigned wB0 = pk2(sv[ba + 4], sv[ba + 5]);
          unsigned wB1 = pk2(sv[ba + 6], sv[ba + 7]);
          unsigned z0 = (unsigned)__shfl_xor((int)(hi ? wA0 : wB0), 32, 64);
          unsigned z1 = (unsigned)__shfl_xor((int)(hi ? wA1 : wB1), 32, 64);
          pa_[kc][0] = hi ? (int)z0 : (int)wA0;
          pa_[kc][1] = hi ? (int)z1 : (int)wA1;
          pa_[kc][2] = hi ? (int)wB0 : (int)z0;
          pa_[kc][3] = hi ? (int)wB1 : (int)z1;
        }
        const char* Vt = smem + 2 * KBYT + (t & 1) * VBYT;
        #pragma unroll
        for (int dht = 0; dht < 4; ++dht) {
          const int dh = dht * 32 + l31;
          short8v vf[4];
          #pragma unroll
          for (int kc = 0; kc < 4; ++kc)
            vf[kc] = *(const short8v*)(Vt + dh * VSTR + kc * 32 + hi * 16);
          #pragma unroll
          for (int kc = 0; kc < 4; ++kc) {
            union { int i[4]; short8v v; } bv;
            bv.i[0] = pa_[kc][0]; bv.i[1] = pa_[kc][1];
            bv.i[2] = pa_[kc][2]; bv.i[3] = pa_[kc][3];
            o[dht] = __builtin_amdgcn_mfma_f32_32x32x16_bf16(vf[kc], bv.v, o[dht], 0, 0, 0);
          }
        }
      }
      if (more) v_write(t + 1, vr);
      __syncthreads();
    }

    const float linv = 1.0f / l_;
    const long orow = (rowbase + qw0 + l31) * DMODEL + h * DHEAD;
    #pragma unroll
    for (int dht = 0; dht < 4; ++dht)
      #pragma unroll
      for (int rg = 0; rg < 4; ++rg) {
        union { __hip_bfloat16 hh[4]; uint2 u; } pk;
        #pragma unroll
        for (int i = 0; i < 4; ++i) pk.hh[i] = __float2bfloat16(o[dht][rg * 4 + i] * linv);
        *(uint2*)(out + orow + dht * 32 + 8 * rg + 4 * hi) = pk.u;
      }
  }
}

// ---------------------------------------------------------------- launch
extern "C" void kernel_launch(void* const* d_in, const int* in_sizes, int n_in,
                              void* d_out, int out_size, void* d_ws, size_t ws_size,
                              hipStream_t stream) {
  const float* hidden  = (const float*)d_in[0];
  const float* ln1w    = (const float*)d_in[1];
  const float* ln1b    = (const float*)d_in[2];
  const float* qkvw    = (const float*)d_in[3];
  const float* qkvb    = (const float*)d_in[4];
  const float* densew  = (const float*)d_in[5];
  const float* denseb  = (const float*)d_in[6];
  const float* ln2w    = (const float*)d_in[7];
  const float* ln2b    = (const float*)d_in[8];
  const float* fc1w    = (const float*)d_in[9];
  const float* fc1b    = (const float*)d_in[10];
  const float* fc2w    = (const float*)d_in[11];
  const float* fc2b    = (const float*)d_in[12];

  char* ws = (char*)d_ws;
  size_t off = 0;
  auto alloc = [&](size_t bytes) { char* p = ws + off; off += (bytes + 255) & ~(size_t)255; return p; };
  __hip_bfloat16* xbf    = (__hip_bfloat16*)alloc((size_t)TOK * DMODEL * 2);
  __hip_bfloat16* wqkv   = (__hip_bfloat16*)alloc((size_t)TD * DMODEL * 2);
  __hip_bfloat16* wdense = (__hip_bfloat16*)alloc((size_t)DMODEL * DMODEL * 2);
  __hip_bfloat16* wfc1   = (__hip_bfloat16*)alloc((size_t)FFDIM * DMODEL * 2);
  __hip_bfloat16* wfc2   = (__hip_bfloat16*)alloc((size_t)DMODEL * FFDIM * 2);
  __hip_bfloat16* big    = (__hip_bfloat16*)alloc((size_t)TOK * FFDIM * 2);
  float*          x2     = (float*)alloc((size_t)TOK * DMODEL * 4);
  __hip_bfloat16* qkvbuf  = big;
  __hip_bfloat16* attnout = big + (size_t)TOK * TD;
  __hip_bfloat16* gelubuf = big;

  // all four weight conversions in one launch
  f2bf4_kernel<<<2048, 256, 0, stream>>>(qkvw,   wqkv,   (long)TD * DMODEL,
                                         densew, wdense, (long)DMODEL * DMODEL,
                                         fc1w,   wfc1,   (long)FFDIM * DMODEL,
                                         fc2w,   wfc2,   (long)DMODEL * FFDIM);

  ln_kernel<<<TOK, 256, 0, stream>>>(hidden, ln1w, ln1b, xbf);
  gemm128ra<0><<<dim3(TD / 128, TOK / 256), 512, 0, stream>>>(xbf, wqkv, qkvb, nullptr, qkvbuf, TD, DMODEL);
  attn_kernel<<<dim3(8, 2 * NHEAD), 256, 0, stream>>>(qkvbuf, attnout);
  gemm128ra<1><<<dim3(DMODEL / 128, TOK / 256), 512, 0, stream>>>(attnout, wdense, denseb, hidden, x2, DMODEL, DMODEL);
  ln_kernel<<<TOK, 256, 0, stream>>>(x2, ln2w, ln2b, xbf);
  gemm128ra<2><<<dim3(FFDIM / 128, TOK / 256), 512, 0, stream>>>(xbf, wfc1, fc1b, nullptr, gelubuf, FFDIM, DMODEL);
  gemm128ra<1><<<dim3(DMODEL / 128, TOK / 256), 512, 0, stream>>>(gelubuf, wfc2, fc2b, x2, (float*)d_out, DMODEL, FFDIM);
}